// Round 14
// baseline (146.056 us; speedup 1.0000x reference)
//
#include <hip/hip_runtime.h>
#include <hip/hip_bf16.h>

// PINN via MFMA — round-13 slim body (per-mt fused, unroll 1) under a
// launch_bounds(64,4) TOTAL-register cap (512/4 = 128 vgpr+agpr).
// Evidence: reported VGPR_Count is arch-only; AGPR side of gfx950's unified
// file kept total >170 -> 2 waves/SIMD -> the immovable "21%" occupancy.
// Round 10 proved the (64,4) cap lifts occupancy to 42% but spilled with the
// fat body (~200 live); round-13's slim body (~100-130 live) should fit.
// Tripwire: FETCH_SIZE ~1.2MB = no spill; ballooning = revert to round 11.
// out = u - dt*(f@alpha^T); uxx enters linearly -> fast path uses
// W5a = W5@alpha^T when l1==0 (exact); generic path kept for l1!=0.
// d_ws layout (1KB frags, lane*16B within frag):
//   [0,64K):        hidden L=0..3, base L*16K: fid=kt*4+mt hi, +8K lo
//   [64K,92K):      W5: fid=kt*7+mt hi (14), +14K lo
//   [92K,106K):     W5a frags: fid=kt*7+mt hi only (14)
//   [106K,134K):    alpha frags (28, no lo)  [fallback path]
//   [134K,154K):    W5a dense fp32 [50][100]

#define NPTS 262144
#define HW   50
#define Q    100
#define BLK  64
#define SPW  32
#define SPB  32
#define NBLK (NPTS / SPB)

#define WS_W5    65536
#define WS_W5AF  94208
#define WS_ALPHA 108544
#define WS_DENSE 137216

typedef float f32x4 __attribute__((ext_vector_type(4)));
typedef short bf16x8 __attribute__((ext_vector_type(8)));
typedef unsigned int u32x4 __attribute__((ext_vector_type(4)));

#define MFMA __builtin_amdgcn_mfma_f32_16x16x32_bf16

__device__ __forceinline__ unsigned int pack_bf2(float a, float b) {
    __hip_bfloat162 h = __float22bfloat162_rn(make_float2(a, b));
    unsigned int u;
    __builtin_memcpy(&u, &h, 4);   // bit-extract; __hip_bfloat162 not trivially copyable
    return u;
}
__device__ __forceinline__ float lo_f(unsigned int p) {   // low bf16 as float
    return __builtin_bit_cast(float, p << 16);
}
__device__ __forceinline__ float hi_f(unsigned int p) {   // high bf16 as float
    return __builtin_bit_cast(float, p & 0xffff0000u);
}
__device__ __forceinline__ float fast_tanh(float z) {
    float e = __expf(2.0f * z);
    return 1.0f - __fdividef(2.0f, e + 1.0f);
}

// ---------- setup 1: dense W5a[i][q] = sum_j W5[i][j] * alpha[q][j] ----------
__global__ void __launch_bounds__(256, 1)
compute_w5a(const float* __restrict__ W5, const float* __restrict__ alpha,
            float* __restrict__ w5a)
{
    int idx = blockIdx.x * 256 + threadIdx.x;      // 0..4999
    if (idx >= HW * Q) return;
    int i = idx / Q, q = idx - i * Q;
    float acc = 0.0f;
    for (int j = 0; j < Q; ++j)
        acc = fmaf(W5[i * Q + j], alpha[q * Q + j], acc);
    w5a[idx] = acc;
}

// ---------- setup 2: build all A-fragments into d_ws ----------
__global__ void __launch_bounds__(64, 1)
build_frags(const float* __restrict__ W1, const float* __restrict__ W2,
            const float* __restrict__ W3, const float* __restrict__ W4,
            const float* __restrict__ W5, const float* __restrict__ alpha,
            unsigned char* __restrict__ ws)
{
    const int ln  = threadIdx.x;
    const int fid = blockIdx.x;            // 0..133

    const float* src;
    int ld, kmax, mmax, kt, mt;
    bool trans, isLo;
    size_t dst;

    if (fid < 64) {
        int L = fid >> 4, f = fid & 15;
        src = (L == 0) ? W1 : (L == 1) ? W2 : (L == 2) ? W3 : W4;
        ld = HW; kmax = HW; mmax = HW; trans = true;
        isLo = f >= 8;
        int ff = f & 7;
        kt = ff >> 2; mt = ff & 3;
        dst = (size_t)(L * 16384 + f * 1024);
    } else if (fid < 92) {
        int f = fid - 64;                  // 0..27
        src = W5; ld = Q; kmax = HW; mmax = Q; trans = true;
        isLo = f >= 14;
        int ff = isLo ? f - 14 : f;
        kt = ff / 7; mt = ff % 7;
        dst = (size_t)(WS_W5 + f * 1024);
    } else if (fid < 106) {
        int f = fid - 92;                  // 0..13, W5a hi frags
        src = (const float*)(ws + WS_DENSE);
        ld = Q; kmax = HW; mmax = Q; trans = true;
        isLo = false;
        kt = f / 7; mt = f % 7;
        dst = (size_t)(WS_W5AF + f * 1024);
    } else {
        int f = fid - 106;                 // 0..27, alpha (fallback)
        src = alpha; ld = Q; kmax = Q; mmax = Q; trans = false;
        isLo = false;
        kt = f / 7; mt = f % 7;
        dst = (size_t)(WS_ALPHA + f * 1024);
    }

    int m  = mt * 16 + (ln & 15);
    int kb = kt * 32 + (ln >> 4) * 8;
    bool mv = (m < mmax);
    unsigned int wout[4];
#pragma unroll
    for (int jj = 0; jj < 4; ++jj) {
        int k0 = kb + 2 * jj, k1 = k0 + 1;
        float v0 = (mv && k0 < kmax) ? (trans ? src[k0 * ld + m] : src[m * ld + k0]) : 0.0f;
        float v1 = (mv && k1 < kmax) ? (trans ? src[k1 * ld + m] : src[m * ld + k1]) : 0.0f;
        unsigned int h = pack_bf2(v0, v1);
        if (isLo)
            wout[jj] = pack_bf2(v0 - lo_f(h), v1 - hi_f(h));
        else
            wout[jj] = h;
    }
    *(uint4*)(ws + dst + ln * 16) = make_uint4(wout[0], wout[1], wout[2], wout[3]);
}

// ---------- main kernel -----------------------------------------------------
__global__ void __launch_bounds__(BLK, 4)
pinn_mfma(const float* __restrict__ b0v, const float* __restrict__ W0,
          const float* __restrict__ b1, const float* __restrict__ b2,
          const float* __restrict__ b3, const float* __restrict__ b4,
          const float* __restrict__ b5,
          const float* __restrict__ x, const float* __restrict__ lam1p,
          const float* __restrict__ lam2p, const float* __restrict__ dtp,
          const unsigned char* __restrict__ ws, float* __restrict__ out)
{
    __shared__ __align__(16) unsigned char statebuf[16384];

    const int lane = threadIdx.x & 63;
    const int l15  = lane & 15;
    const int g    = lane >> 4;
    const int sbase = blockIdx.x * SPB;

    unsigned char* stHh  = &statebuf[0];       // h hi   [32 samp][128B]
    unsigned char* stHl  = &statebuf[4096];    // h lo
    unsigned char* stHx  = &statebuf[8192];    // hx
    unsigned char* stHxx = &statebuf[12288];   // hxx
    const unsigned char* wgl = ws + lane * 16; // per-lane base into frag store
    const int swz = (l15 & 7) << 4;   // samp&7 == l15&7 (samp = 16nt + l15)

    const f32x4 Z4 = {0.0f, 0.0f, 0.0f, 0.0f};

    // persistent state B-fragments: B[k=ch][n=samp], elem j -> ch = 32kt+8g+j
    bf16x8 Bh_hi[2][2], Bh_lo[2][2], Bx[2][2], Bxx[2][2];

    // ---------- layer 0: 1 -> 50 (analytic, elementwise) ----------
    {
        float xv[2];
        xv[0] = x[sbase + l15];
        xv[1] = x[sbase + 16 + l15];
#pragma unroll
        for (int kt = 0; kt < 2; ++kt) {
            float wv[8], bv[8];
#pragma unroll
            for (int j = 0; j < 8; ++j) {
                int ch = kt * 32 + g * 8 + j;
                wv[j] = (ch < HW) ? W0[ch] : 0.0f;
                bv[j] = (ch < HW) ? b0v[ch] : 0.0f;
            }
#pragma unroll
            for (int nt = 0; nt < 2; ++nt) {
                u32x4 uh, ul, ux, uxx;
#pragma unroll
                for (int jp = 0; jp < 4; ++jp) {
                    float t0 = fast_tanh(fmaf(xv[nt], wv[2*jp],   bv[2*jp]));
                    float t1 = fast_tanh(fmaf(xv[nt], wv[2*jp+1], bv[2*jp+1]));
                    float s0 = 1.0f - t0 * t0, s1 = 1.0f - t1 * t1;
                    float hx0 = s0 * wv[2*jp],   hx1 = s1 * wv[2*jp+1];
                    float hxx0 = -2.0f * t0 * hx0 * wv[2*jp];
                    float hxx1 = -2.0f * t1 * hx1 * wv[2*jp+1];
                    unsigned int h = pack_bf2(t0, t1);
                    uh[jp]  = h;
                    ul[jp]  = pack_bf2(t0 - lo_f(h), t1 - hi_f(h));
                    ux[jp]  = pack_bf2(hx0, hx1);
                    uxx[jp] = pack_bf2(hxx0, hxx1);
                }
                Bh_hi[kt][nt] = __builtin_bit_cast(bf16x8, uh);
                Bh_lo[kt][nt] = __builtin_bit_cast(bf16x8, ul);
                Bx[kt][nt]    = __builtin_bit_cast(bf16x8, ux);
                Bxx[kt][nt]   = __builtin_bit_cast(bf16x8, uxx);
            }
        }
    }

    // ---------- 4 hidden layers 50 -> 50, per-mt fused, mt NOT unrolled ------
    for (int L = 0; L < 4; ++L) {
        const float* bl = (L == 0) ? b1 : (L == 1) ? b2 : (L == 2) ? b3 : b4;
        const unsigned char* wfl = wgl + L * 16384;

#pragma unroll 1
        for (int mt = 0; mt < 4; ++mt) {
            // small per-mt accumulator set: 3 streams x 2 nt = 24 regs
            f32x4 at[2], ax[2], axx[2];
#pragma unroll
            for (int nt = 0; nt < 2; ++nt) {
#pragma unroll
                for (int r = 0; r < 4; ++r) {
                    int ch = mt * 16 + g * 4 + r;
                    at[nt][r] = (ch < HW) ? bl[ch] : 0.0f;   // bias pre-seed
                }
                ax[nt] = Z4; axx[nt] = Z4;
            }
#pragma unroll
            for (int kt = 0; kt < 2; ++kt) {
                bf16x8 Ahi = *(const bf16x8*)(wfl + (kt * 4 + mt) * 1024);
                bf16x8 Alo = *(const bf16x8*)(wfl + (8 + kt * 4 + mt) * 1024);
#pragma unroll
                for (int nt = 0; nt < 2; ++nt) {
                    at[nt]  = MFMA(Ahi, Bh_hi[kt][nt], at[nt],  0, 0, 0);
                    at[nt]  = MFMA(Ahi, Bh_lo[kt][nt], at[nt],  0, 0, 0);
                    at[nt]  = MFMA(Alo, Bh_hi[kt][nt], at[nt],  0, 0, 0);
                    ax[nt]  = MFMA(Ahi, Bx[kt][nt],  ax[nt],  0, 0, 0);
                    axx[nt] = MFMA(Ahi, Bxx[kt][nt], axx[nt], 0, 0, 0);
                }
            }
            // fused tanh + derivative combine + pack + stage (all 4 streams)
#pragma unroll
            for (int nt = 0; nt < 2; ++nt) {
                float t[4], hx[4], hxx[4];
#pragma unroll
                for (int r = 0; r < 4; ++r) {
                    float tv  = fast_tanh(at[nt][r]);
                    float s   = fmaf(-tv, tv, 1.0f);
                    float zx  = ax[nt][r];
                    float zxx = axx[nt][r];
                    t[r]   = tv;
                    hx[r]  = s * zx;
                    hxx[r] = fmaf(s, zxx, -2.0f * tv * zx * hx[r]);
                }
                unsigned int h0 = pack_bf2(t[0], t[1]);
                unsigned int h1 = pack_bf2(t[2], t[3]);
                unsigned int l0 = pack_bf2(t[0] - lo_f(h0), t[1] - hi_f(h0));
                unsigned int l1 = pack_bf2(t[2] - lo_f(h1), t[3] - hi_f(h1));
                unsigned int a0 = pack_bf2(hx[0], hx[1]);
                unsigned int a1 = pack_bf2(hx[2], hx[3]);
                unsigned int c0 = pack_bf2(hxx[0], hxx[1]);
                unsigned int c1 = pack_bf2(hxx[2], hxx[3]);
                int off = ((nt * 16 + l15) * 128 + (mt * 16 + g * 4) * 2) ^ swz;
                *(uint2*)(stHh  + off) = make_uint2(h0, h1);
                *(uint2*)(stHl  + off) = make_uint2(l0, l1);
                *(uint2*)(stHx  + off) = make_uint2(a0, a1);
                *(uint2*)(stHxx + off) = make_uint2(c0, c1);
            }
        }
        // reload all B-frags (LDS ops are in-order per wave; wait before use)
#pragma unroll
        for (int kt = 0; kt < 2; ++kt)
#pragma unroll
            for (int nt = 0; nt < 2; ++nt) {
                int off = ((nt * 16 + l15) * 128 + (kt * 32 + g * 8) * 2) ^ swz;
                Bh_hi[kt][nt] = *(const bf16x8*)(stHh  + off);
                Bh_lo[kt][nt] = *(const bf16x8*)(stHl  + off);
                Bx[kt][nt]    = *(const bf16x8*)(stHx  + off);
                Bxx[kt][nt]   = *(const bf16x8*)(stHxx + off);
            }
        asm volatile("s_waitcnt lgkmcnt(0)" ::: "memory");
    }

    const float lam1 = lam1p[0];
    const float el2  = __expf(lam2p[0]);
    const float dtv  = dtp[0];

    const unsigned char* w5f = wgl + WS_W5;
    unsigned char* st0 = stHh;   // reuse for epilogue staging

    if (lam1 == 0.0f) {
        // ======== FAST PATH: out = (h@W5+b5) - dt*el2*(hxx@W5a) ========
        const unsigned char* waf = wgl + WS_W5AF;
        const float c = dtv * el2;
#pragma unroll 1
        for (int mt = 0; mt < 7; ++mt) {
            f32x4 au[2], acr[2];
#pragma unroll
            for (int nt = 0; nt < 2; ++nt) {
#pragma unroll
                for (int r = 0; r < 4; ++r) {
                    int q = mt * 16 + g * 4 + r;
                    au[nt][r] = (q < Q) ? b5[q] : 0.0f;
                }
                acr[nt] = Z4;
            }
#pragma unroll
            for (int kt = 0; kt < 2; ++kt) {
                bf16x8 Ahi = *(const bf16x8*)(w5f + (kt * 7 + mt) * 1024);
                bf16x8 Alo = *(const bf16x8*)(w5f + (14 + kt * 7 + mt) * 1024);
                bf16x8 Aa  = *(const bf16x8*)(waf + (kt * 7 + mt) * 1024);
#pragma unroll
                for (int nt = 0; nt < 2; ++nt) {
                    au[nt]  = MFMA(Ahi, Bh_hi[kt][nt], au[nt],  0, 0, 0);
                    au[nt]  = MFMA(Ahi, Bh_lo[kt][nt], au[nt],  0, 0, 0);
                    au[nt]  = MFMA(Alo, Bh_hi[kt][nt], au[nt],  0, 0, 0);
                    acr[nt] = MFMA(Aa,  Bxx[kt][nt],   acr[nt], 0, 0, 0);
                }
            }
            // combine, stage [32 samp][16 q] fp32, coalesced store
#pragma unroll
            for (int nt = 0; nt < 2; ++nt) {
                int s = nt * 16 + l15;
                f32x4 ov;
#pragma unroll
                for (int r = 0; r < 4; ++r)
                    ov[r] = fmaf(-c, acr[nt][r], au[nt][r]);
                *(f32x4*)(st0 + s * 64 + g * 16) = ov;
            }
            asm volatile("s_waitcnt lgkmcnt(0)" ::: "memory");
#pragma unroll
            for (int p = 0; p < 2; ++p) {
                int s  = p * 16 + (lane >> 2);
                int qi = (lane & 3) * 4;
                f32x4 v = *(const f32x4*)(st0 + s * 64 + qi * 4);
                int qb = mt * 16 + qi;
                if (qb < Q)
                    *(f32x4*)(&out[(size_t)(sbase + s) * Q + qb]) = v;
            }
            asm volatile("s_waitcnt lgkmcnt(0)" ::: "memory");
        }
    } else {
        // ======== GENERIC PATH (round-8 arithmetic, mt not unrolled) ========
        f32x4 u_all[7][2];
#pragma unroll 1
        for (int mt = 0; mt < 7; ++mt) {
            f32x4 au[2], aux_[2], auxx[2];
#pragma unroll
            for (int nt = 0; nt < 2; ++nt) {
#pragma unroll
                for (int r = 0; r < 4; ++r) {
                    int q = mt * 16 + g * 4 + r;
                    au[nt][r] = (q < Q) ? b5[q] : 0.0f;
                }
                aux_[nt] = Z4; auxx[nt] = Z4;
            }
#pragma unroll
            for (int kt = 0; kt < 2; ++kt) {
                bf16x8 Ahi = *(const bf16x8*)(w5f + (kt * 7 + mt) * 1024);
                bf16x8 Alo = *(const bf16x8*)(w5f + (14 + kt * 7 + mt) * 1024);
#pragma unroll
                for (int nt = 0; nt < 2; ++nt) {
                    au[nt]   = MFMA(Ahi, Bh_hi[kt][nt], au[nt],   0, 0, 0);
                    au[nt]   = MFMA(Ahi, Bh_lo[kt][nt], au[nt],   0, 0, 0);
                    au[nt]   = MFMA(Alo, Bh_hi[kt][nt], au[nt],   0, 0, 0);
                    aux_[nt] = MFMA(Ahi, Bx[kt][nt],  aux_[nt], 0, 0, 0);
                    auxx[nt] = MFMA(Ahi, Bxx[kt][nt], auxx[nt], 0, 0, 0);
                }
            }
#pragma unroll
            for (int nt = 0; nt < 2; ++nt) {
                float fv[4];
#pragma unroll
                for (int r = 0; r < 4; ++r) {
                    int q = mt * 16 + g * 4 + r;
                    float u = au[nt][r];
                    u_all[mt][nt][r] = u;
                    float f = fmaf(-lam1 * u, aux_[nt][r], el2 * auxx[nt][r]);
                    fv[r] = (q < Q) ? f : 0.0f;
                }
                unsigned int f0 = pack_bf2(fv[0], fv[1]);
                unsigned int f1 = pack_bf2(fv[2], fv[3]);
                int s = nt * 16 + l15;
                int off = (s * 256 + (mt * 16 + g * 4) * 2) ^ swz;
                *(uint2*)(st0 + off) = make_uint2(f0, f1);
            }
        }

        bf16x8 Ff[4][2];
#pragma unroll
        for (int kt = 0; kt < 4; ++kt)
#pragma unroll
            for (int nt = 0; nt < 2; ++nt) {
                int s = nt * 16 + l15;
                int off = (s * 256 + (kt * 32 + g * 8) * 2) ^ swz;
                Ff[kt][nt] = *(const bf16x8*)(st0 + off);
            }
        asm volatile("s_waitcnt lgkmcnt(0)" ::: "memory");
        {
            const bf16x8 z8 = {0, 0, 0, 0, 0, 0, 0, 0};
            if (g >= 2) { Ff[3][0] = z8; Ff[3][1] = z8; }
        }

        const unsigned char* alf = wgl + WS_ALPHA;
#pragma unroll 1
        for (int mt = 0; mt < 7; ++mt) {
            f32x4 ac[2]; ac[0] = Z4; ac[1] = Z4;
#pragma unroll
            for (int kt = 0; kt < 4; ++kt) {
                bf16x8 Aa = *(const bf16x8*)(alf + (kt * 7 + mt) * 1024);
#pragma unroll
                for (int nt = 0; nt < 2; ++nt)
                    ac[nt] = MFMA(Aa, Ff[kt][nt], ac[nt], 0, 0, 0);
            }
#pragma unroll
            for (int nt = 0; nt < 2; ++nt) {
                int s = nt * 16 + l15;
                f32x4 ov;
#pragma unroll
                for (int r = 0; r < 4; ++r)
                    ov[r] = fmaf(-dtv, ac[nt][r], u_all[mt][nt][r]);
                *(f32x4*)(st0 + s * 64 + g * 16) = ov;
            }
            asm volatile("s_waitcnt lgkmcnt(0)" ::: "memory");
#pragma unroll
            for (int p = 0; p < 2; ++p) {
                int s  = p * 16 + (lane >> 2);
                int qi = (lane & 3) * 4;
                f32x4 v = *(const f32x4*)(st0 + s * 64 + qi * 4);
                int qb = mt * 16 + qi;
                if (qb < Q)
                    *(f32x4*)(&out[(size_t)(sbase + s) * Q + qb]) = v;
            }
            asm volatile("s_waitcnt lgkmcnt(0)" ::: "memory");
        }
    }
}

extern "C" void kernel_launch(void* const* d_in, const int* in_sizes, int n_in,
                              void* d_out, int out_size, void* d_ws, size_t ws_size,
                              hipStream_t stream) {
    const float* W0 = (const float*)d_in[0];
    const float* b0 = (const float*)d_in[1];
    const float* W1 = (const float*)d_in[2];
    const float* b1 = (const float*)d_in[3];
    const float* W2 = (const float*)d_in[4];
    const float* b2 = (const float*)d_in[5];
    const float* W3 = (const float*)d_in[6];
    const float* b3 = (const float*)d_in[7];
    const float* W4 = (const float*)d_in[8];
    const float* b4 = (const float*)d_in[9];
    const float* W5 = (const float*)d_in[10];
    const float* b5 = (const float*)d_in[11];
    const float* x     = (const float*)d_in[12];
    const float* lam1  = (const float*)d_in[13];
    const float* lam2  = (const float*)d_in[14];
    const float* alpha = (const float*)d_in[15];
    const float* dt    = (const float*)d_in[16];

    unsigned char* ws = (unsigned char*)d_ws;

    compute_w5a<<<20, 256, 0, stream>>>(W5, alpha, (float*)(ws + WS_DENSE));
    build_frags<<<134, 64, 0, stream>>>(W1, W2, W3, W4, W5, alpha, ws);
    pinn_mfma<<<NBLK, BLK, 0, stream>>>(b0, W0, b1, b2, b3, b4, b5,
                                        x, lam1, lam2, dt,
                                        (const unsigned char*)ws, (float*)d_out);
}

// Round 15
// 133.963 us; speedup vs baseline: 1.0903x; 1.0903x over previous
//
#include <hip/hip_runtime.h>
#include <hip/hip_bf16.h>

// PINN via MFMA — round-11 optimum (124.9us), consolidated.
// 1-wave workgroups, launch_bounds(64,2) (uncapped regs, VGPR 96, no spill),
// full unroll (best per-wave ILP; TLP is hardware-capped at ~2 waves/SIMD
// regardless of register use — verified across 5 structural variants).
// Setup folded to ONE kernel: build_frags computes W5a = W5@alpha^T inline
// for its 14 fragments (drops the compute_w5a launch from every replay).
// out = u - dt*(f@alpha^T); uxx enters linearly -> fast path uses W5a when
// l1==0 (exact); generic path kept for l1!=0.
// d_ws layout (1KB frags, lane*16B within frag):
//   [0,64K):        hidden L=0..3, base L*16K: fid=kt*4+mt hi, +8K lo
//   [64K,92K):      W5: fid=kt*7+mt hi (14), +14K lo
//   [92K,106K):     W5a frags: fid=kt*7+mt hi only (14)
//   [106K,134K):    alpha frags (28, no lo)  [fallback path]

#define NPTS 262144
#define HW   50
#define Q    100
#define BLK  64
#define SPW  32
#define SPB  32
#define NBLK (NPTS / SPB)

#define WS_W5    65536
#define WS_W5AF  94208
#define WS_ALPHA 108544

typedef float f32x4 __attribute__((ext_vector_type(4)));
typedef short bf16x8 __attribute__((ext_vector_type(8)));
typedef unsigned int u32x4 __attribute__((ext_vector_type(4)));

#define MFMA __builtin_amdgcn_mfma_f32_16x16x32_bf16

__device__ __forceinline__ unsigned int pack_bf2(float a, float b) {
    __hip_bfloat162 h = __float22bfloat162_rn(make_float2(a, b));
    unsigned int u;
    __builtin_memcpy(&u, &h, 4);   // bit-extract; __hip_bfloat162 not trivially copyable
    return u;
}
__device__ __forceinline__ float lo_f(unsigned int p) {   // low bf16 as float
    return __builtin_bit_cast(float, p << 16);
}
__device__ __forceinline__ float hi_f(unsigned int p) {   // high bf16 as float
    return __builtin_bit_cast(float, p & 0xffff0000u);
}
__device__ __forceinline__ float fast_tanh(float z) {
    float e = __expf(2.0f * z);
    return 1.0f - __fdividef(2.0f, e + 1.0f);
}

// ---------- setup: build all A-fragments into d_ws (one kernel) ----------
__global__ void __launch_bounds__(64, 1)
build_frags(const float* __restrict__ W1, const float* __restrict__ W2,
            const float* __restrict__ W3, const float* __restrict__ W4,
            const float* __restrict__ W5, const float* __restrict__ alpha,
            unsigned char* __restrict__ ws)
{
    const int ln  = threadIdx.x;
    const int fid = blockIdx.x;            // 0..133

    if (fid >= 92 && fid < 106) {
        // W5a frags computed inline: A[m][k] = W5a[k][m] = sum_j W5[k][j]*alpha[m][j]
        int f  = fid - 92;                 // 0..13
        int kt = f / 7, mt = f % 7;
        int m  = mt * 16 + (ln & 15);      // q column
        int kb = kt * 32 + (ln >> 4) * 8;  // i row base
        unsigned int wout[4];
#pragma unroll
        for (int jj = 0; jj < 4; ++jj) {
            int k0 = kb + 2 * jj, k1 = k0 + 1;
            float v0 = 0.0f, v1 = 0.0f;
            if (m < Q) {
                if (k0 < HW)
                    for (int j = 0; j < Q; ++j)
                        v0 = fmaf(W5[k0 * Q + j], alpha[m * Q + j], v0);
                if (k1 < HW)
                    for (int j = 0; j < Q; ++j)
                        v1 = fmaf(W5[k1 * Q + j], alpha[m * Q + j], v1);
            }
            wout[jj] = pack_bf2(v0, v1);
        }
        *(uint4*)(ws + WS_W5AF + (size_t)f * 1024 + ln * 16)
            = make_uint4(wout[0], wout[1], wout[2], wout[3]);
        return;
    }

    const float* src;
    int ld, kmax, mmax, kt, mt;
    bool trans, isLo;
    size_t dst;

    if (fid < 64) {
        int L = fid >> 4, f = fid & 15;
        src = (L == 0) ? W1 : (L == 1) ? W2 : (L == 2) ? W3 : W4;
        ld = HW; kmax = HW; mmax = HW; trans = true;
        isLo = f >= 8;
        int ff = f & 7;
        kt = ff >> 2; mt = ff & 3;
        dst = (size_t)(L * 16384 + f * 1024);
    } else if (fid < 92) {
        int f = fid - 64;                  // 0..27
        src = W5; ld = Q; kmax = HW; mmax = Q; trans = true;
        isLo = f >= 14;
        int ff = isLo ? f - 14 : f;
        kt = ff / 7; mt = ff % 7;
        dst = (size_t)(WS_W5 + f * 1024);
    } else {
        int f = fid - 106;                 // 0..27, alpha (fallback path)
        src = alpha; ld = Q; kmax = Q; mmax = Q; trans = false;
        isLo = false;
        kt = f / 7; mt = f % 7;
        dst = (size_t)(WS_ALPHA + f * 1024);
    }

    int m  = mt * 16 + (ln & 15);
    int kb = kt * 32 + (ln >> 4) * 8;
    bool mv = (m < mmax);
    unsigned int wout[4];
#pragma unroll
    for (int jj = 0; jj < 4; ++jj) {
        int k0 = kb + 2 * jj, k1 = k0 + 1;
        float v0 = (mv && k0 < kmax) ? (trans ? src[k0 * ld + m] : src[m * ld + k0]) : 0.0f;
        float v1 = (mv && k1 < kmax) ? (trans ? src[k1 * ld + m] : src[m * ld + k1]) : 0.0f;
        unsigned int h = pack_bf2(v0, v1);
        if (isLo)
            wout[jj] = pack_bf2(v0 - lo_f(h), v1 - hi_f(h));
        else
            wout[jj] = h;
    }
    *(uint4*)(ws + dst + ln * 16) = make_uint4(wout[0], wout[1], wout[2], wout[3]);
}

// ---------- main kernel -----------------------------------------------------
__global__ void __launch_bounds__(BLK, 2)
pinn_mfma(const float* __restrict__ b0v, const float* __restrict__ W0,
          const float* __restrict__ b1, const float* __restrict__ b2,
          const float* __restrict__ b3, const float* __restrict__ b4,
          const float* __restrict__ b5,
          const float* __restrict__ x, const float* __restrict__ lam1p,
          const float* __restrict__ lam2p, const float* __restrict__ dtp,
          const unsigned char* __restrict__ ws, float* __restrict__ out)
{
    __shared__ __align__(16) unsigned char statebuf[8192];

    const int lane = threadIdx.x & 63;
    const int l15  = lane & 15;
    const int g    = lane >> 4;
    const int sbase = blockIdx.x * SPB;

    unsigned char* st0 = &statebuf[0];
    unsigned char* st1 = &statebuf[4096];
    const unsigned char* wgl = ws + lane * 16;   // per-lane base into frag store
    const int swz = (l15 & 7) << 4;   // samp&7 == l15&7 (samp = 16nt + l15)

    const f32x4 Z4 = {0.0f, 0.0f, 0.0f, 0.0f};

    // persistent state B-fragments: B[k=ch][n=samp], elem j -> ch = 32kt+8g+j
    bf16x8 Bh_hi[2][2], Bh_lo[2][2], Bx[2][2], Bxx[2][2];

    // ---------- layer 0: 1 -> 50 (analytic, elementwise) ----------
    {
        float xv[2];
        xv[0] = x[sbase + l15];
        xv[1] = x[sbase + 16 + l15];
#pragma unroll
        for (int kt = 0; kt < 2; ++kt) {
            float wv[8], bv[8];
#pragma unroll
            for (int j = 0; j < 8; ++j) {
                int ch = kt * 32 + g * 8 + j;
                wv[j] = (ch < HW) ? W0[ch] : 0.0f;
                bv[j] = (ch < HW) ? b0v[ch] : 0.0f;
            }
#pragma unroll
            for (int nt = 0; nt < 2; ++nt) {
                u32x4 uh, ul, ux, uxx;
#pragma unroll
                for (int jp = 0; jp < 4; ++jp) {
                    float t0 = fast_tanh(fmaf(xv[nt], wv[2*jp],   bv[2*jp]));
                    float t1 = fast_tanh(fmaf(xv[nt], wv[2*jp+1], bv[2*jp+1]));
                    float s0 = 1.0f - t0 * t0, s1 = 1.0f - t1 * t1;
                    float hx0 = s0 * wv[2*jp],   hx1 = s1 * wv[2*jp+1];
                    float hxx0 = -2.0f * t0 * hx0 * wv[2*jp];
                    float hxx1 = -2.0f * t1 * hx1 * wv[2*jp+1];
                    unsigned int h = pack_bf2(t0, t1);
                    uh[jp]  = h;
                    ul[jp]  = pack_bf2(t0 - lo_f(h), t1 - hi_f(h));
                    ux[jp]  = pack_bf2(hx0, hx1);
                    uxx[jp] = pack_bf2(hxx0, hxx1);
                }
                Bh_hi[kt][nt] = __builtin_bit_cast(bf16x8, uh);
                Bh_lo[kt][nt] = __builtin_bit_cast(bf16x8, ul);
                Bx[kt][nt]    = __builtin_bit_cast(bf16x8, ux);
                Bxx[kt][nt]   = __builtin_bit_cast(bf16x8, uxx);
            }
        }
    }

    // ---------- 4 hidden layers 50 -> 50 ----------
    for (int L = 0; L < 4; ++L) {
        const float* bl = (L == 0) ? b1 : (L == 1) ? b2 : (L == 2) ? b3 : b4;
        const unsigned char* wfl = wgl + L * 16384;

        float bb[4][4];
#pragma unroll
        for (int mt = 0; mt < 4; ++mt)
#pragma unroll
            for (int r = 0; r < 4; ++r) {
                int ch = mt * 16 + g * 4 + r;
                bb[mt][r] = (ch < HW) ? bl[ch] : 0.0f;
            }

        // accumulators; at pre-seeded with bias (saves the add before tanh)
        f32x4 at[4][2], ax[4][2], axx[4][2];
#pragma unroll
        for (int mt = 0; mt < 4; ++mt)
#pragma unroll
            for (int nt = 0; nt < 2; ++nt) {
#pragma unroll
                for (int r = 0; r < 4; ++r) at[mt][nt][r] = bb[mt][r];
                ax[mt][nt] = Z4; axx[mt][nt] = Z4;
            }

#pragma unroll
        for (int kt = 0; kt < 2; ++kt) {
#pragma unroll
            for (int mt = 0; mt < 4; ++mt) {
                bf16x8 Ahi = *(const bf16x8*)(wfl + (kt * 4 + mt) * 1024);
                bf16x8 Alo = *(const bf16x8*)(wfl + (8 + kt * 4 + mt) * 1024);
#pragma unroll
                for (int nt = 0; nt < 2; ++nt) {
                    at[mt][nt]  = MFMA(Ahi, Bh_hi[kt][nt], at[mt][nt], 0, 0, 0);
                    at[mt][nt]  = MFMA(Ahi, Bh_lo[kt][nt], at[mt][nt], 0, 0, 0);
                    at[mt][nt]  = MFMA(Alo, Bh_hi[kt][nt], at[mt][nt], 0, 0, 0);
                    ax[mt][nt]  = MFMA(Ahi, Bx[kt][nt],  ax[mt][nt],  0, 0, 0);
                    axx[mt][nt] = MFMA(Ahi, Bxx[kt][nt], axx[mt][nt], 0, 0, 0);
                }
            }
        }

        // phase A: t = tanh(z); stage hi/lo -> read new Bh frags
#pragma unroll
        for (int mt = 0; mt < 4; ++mt)
#pragma unroll
            for (int nt = 0; nt < 2; ++nt) {
                float t0 = fast_tanh(at[mt][nt][0]);
                float t1 = fast_tanh(at[mt][nt][1]);
                float t2 = fast_tanh(at[mt][nt][2]);
                float t3 = fast_tanh(at[mt][nt][3]);
                at[mt][nt][0] = t0; at[mt][nt][1] = t1;
                at[mt][nt][2] = t2; at[mt][nt][3] = t3;
                unsigned int h0 = pack_bf2(t0, t1);
                unsigned int h1 = pack_bf2(t2, t3);
                unsigned int l0 = pack_bf2(t0 - lo_f(h0), t1 - hi_f(h0));
                unsigned int l1 = pack_bf2(t2 - lo_f(h1), t3 - hi_f(h1));
                int off = ((nt * 16 + l15) * 128 + (mt * 16 + g * 4) * 2) ^ swz;
                *(uint2*)(st0 + off) = make_uint2(h0, h1);
                *(uint2*)(st1 + off) = make_uint2(l0, l1);
            }
#pragma unroll
        for (int kt = 0; kt < 2; ++kt)
#pragma unroll
            for (int nt = 0; nt < 2; ++nt) {
                int off = ((nt * 16 + l15) * 128 + (kt * 32 + g * 8) * 2) ^ swz;
                Bh_hi[kt][nt] = *(const bf16x8*)(st0 + off);
                Bh_lo[kt][nt] = *(const bf16x8*)(st1 + off);
            }
        asm volatile("s_waitcnt lgkmcnt(0)" ::: "memory");

        // phase B: hx = s*zx ; hxx = s*zxx - 2*t*s*zx^2
#pragma unroll
        for (int mt = 0; mt < 4; ++mt)
#pragma unroll
            for (int nt = 0; nt < 2; ++nt) {
                float hx[4], hxx[4];
#pragma unroll
                for (int r = 0; r < 4; ++r) {
                    float t   = at[mt][nt][r];
                    float s   = fmaf(-t, t, 1.0f);
                    float zx  = ax[mt][nt][r];
                    float zxx = axx[mt][nt][r];
                    hx[r]  = s * zx;
                    hxx[r] = fmaf(s, zxx, -2.0f * t * zx * hx[r]);
                }
                unsigned int a0 = pack_bf2(hx[0], hx[1]);
                unsigned int a1 = pack_bf2(hx[2], hx[3]);
                unsigned int c0 = pack_bf2(hxx[0], hxx[1]);
                unsigned int c1 = pack_bf2(hxx[2], hxx[3]);
                int off = ((nt * 16 + l15) * 128 + (mt * 16 + g * 4) * 2) ^ swz;
                *(uint2*)(st0 + off) = make_uint2(a0, a1);
                *(uint2*)(st1 + off) = make_uint2(c0, c1);
            }
#pragma unroll
        for (int kt = 0; kt < 2; ++kt)
#pragma unroll
            for (int nt = 0; nt < 2; ++nt) {
                int off = ((nt * 16 + l15) * 128 + (kt * 32 + g * 8) * 2) ^ swz;
                Bx[kt][nt]  = *(const bf16x8*)(st0 + off);
                Bxx[kt][nt] = *(const bf16x8*)(st1 + off);
            }
        asm volatile("s_waitcnt lgkmcnt(0)" ::: "memory");
    }

    const float lam1 = lam1p[0];
    const float el2  = __expf(lam2p[0]);
    const float dtv  = dtp[0];

    const unsigned char* w5f = wgl + WS_W5;

    if (lam1 == 0.0f) {
        // ======== FAST PATH: out = (h@W5+b5) - dt*el2*(hxx@W5a) ========
        const unsigned char* waf = wgl + WS_W5AF;
        const float c = dtv * el2;
#pragma unroll
        for (int mt = 0; mt < 7; ++mt) {
            f32x4 au[2], acr[2];
#pragma unroll
            for (int nt = 0; nt < 2; ++nt) {
#pragma unroll
                for (int r = 0; r < 4; ++r) {
                    int q = mt * 16 + g * 4 + r;
                    au[nt][r] = (q < Q) ? b5[q] : 0.0f;
                }
                acr[nt] = Z4;
            }
#pragma unroll
            for (int kt = 0; kt < 2; ++kt) {
                bf16x8 Ahi = *(const bf16x8*)(w5f + (kt * 7 + mt) * 1024);
                bf16x8 Alo = *(const bf16x8*)(w5f + (14 + kt * 7 + mt) * 1024);
                bf16x8 Aa  = *(const bf16x8*)(waf + (kt * 7 + mt) * 1024);
#pragma unroll
                for (int nt = 0; nt < 2; ++nt) {
                    au[nt]  = MFMA(Ahi, Bh_hi[kt][nt], au[nt],  0, 0, 0);
                    au[nt]  = MFMA(Ahi, Bh_lo[kt][nt], au[nt],  0, 0, 0);
                    au[nt]  = MFMA(Alo, Bh_hi[kt][nt], au[nt],  0, 0, 0);
                    acr[nt] = MFMA(Aa,  Bxx[kt][nt],   acr[nt], 0, 0, 0);
                }
            }
            // combine, stage [32 samp][16 q] fp32 in st0, coalesced store
#pragma unroll
            for (int nt = 0; nt < 2; ++nt) {
                int s = nt * 16 + l15;
                f32x4 ov;
#pragma unroll
                for (int r = 0; r < 4; ++r)
                    ov[r] = fmaf(-c, acr[nt][r], au[nt][r]);
                *(f32x4*)(st0 + s * 64 + g * 16) = ov;
            }
            asm volatile("s_waitcnt lgkmcnt(0)" ::: "memory");
#pragma unroll
            for (int p = 0; p < 2; ++p) {
                int s  = p * 16 + (lane >> 2);
                int qi = (lane & 3) * 4;
                f32x4 v = *(const f32x4*)(st0 + s * 64 + qi * 4);
                int qb = mt * 16 + qi;
                if (qb < Q)
                    *(f32x4*)(&out[(size_t)(sbase + s) * Q + qb]) = v;
            }
            asm volatile("s_waitcnt lgkmcnt(0)" ::: "memory");
        }
    } else {
        // ======== GENERIC PATH (proven round-8 code) ========
        f32x4 u_all[7][2];
#pragma unroll
        for (int mt = 0; mt < 7; ++mt) {
            f32x4 au[2], aux_[2], auxx[2];
#pragma unroll
            for (int nt = 0; nt < 2; ++nt) {
#pragma unroll
                for (int r = 0; r < 4; ++r) {
                    int q = mt * 16 + g * 4 + r;
                    au[nt][r] = (q < Q) ? b5[q] : 0.0f;
                }
                aux_[nt] = Z4; auxx[nt] = Z4;
            }
#pragma unroll
            for (int kt = 0; kt < 2; ++kt) {
                bf16x8 Ahi = *(const bf16x8*)(w5f + (kt * 7 + mt) * 1024);
                bf16x8 Alo = *(const bf16x8*)(w5f + (14 + kt * 7 + mt) * 1024);
#pragma unroll
                for (int nt = 0; nt < 2; ++nt) {
                    au[nt]   = MFMA(Ahi, Bh_hi[kt][nt], au[nt],   0, 0, 0);
                    au[nt]   = MFMA(Ahi, Bh_lo[kt][nt], au[nt],   0, 0, 0);
                    au[nt]   = MFMA(Alo, Bh_hi[kt][nt], au[nt],   0, 0, 0);
                    aux_[nt] = MFMA(Ahi, Bx[kt][nt],  aux_[nt], 0, 0, 0);
                    auxx[nt] = MFMA(Ahi, Bxx[kt][nt], auxx[nt], 0, 0, 0);
                }
            }
#pragma unroll
            for (int nt = 0; nt < 2; ++nt) {
                float fv[4];
#pragma unroll
                for (int r = 0; r < 4; ++r) {
                    int q = mt * 16 + g * 4 + r;
                    float u = au[nt][r];
                    u_all[mt][nt][r] = u;
                    float f = fmaf(-lam1 * u, aux_[nt][r], el2 * auxx[nt][r]);
                    fv[r] = (q < Q) ? f : 0.0f;
                }
                unsigned int f0 = pack_bf2(fv[0], fv[1]);
                unsigned int f1 = pack_bf2(fv[2], fv[3]);
                int s = nt * 16 + l15;
                int off = (s * 256 + (mt * 16 + g * 4) * 2) ^ swz;
                *(uint2*)(st0 + off) = make_uint2(f0, f1);
            }
        }

        bf16x8 Ff[4][2];
#pragma unroll
        for (int kt = 0; kt < 4; ++kt)
#pragma unroll
            for (int nt = 0; nt < 2; ++nt) {
                int s = nt * 16 + l15;
                int off = (s * 256 + (kt * 32 + g * 8) * 2) ^ swz;
                Ff[kt][nt] = *(const bf16x8*)(st0 + off);
            }
        asm volatile("s_waitcnt lgkmcnt(0)" ::: "memory");
        {
            const bf16x8 z8 = {0, 0, 0, 0, 0, 0, 0, 0};
            if (g >= 2) { Ff[3][0] = z8; Ff[3][1] = z8; }
        }

        const unsigned char* alf = wgl + WS_ALPHA;
#pragma unroll
        for (int mt = 0; mt < 7; ++mt) {
            f32x4 ac[2]; ac[0] = Z4; ac[1] = Z4;
#pragma unroll
            for (int kt = 0; kt < 4; ++kt) {
                bf16x8 Aa = *(const bf16x8*)(alf + (kt * 7 + mt) * 1024);
#pragma unroll
                for (int nt = 0; nt < 2; ++nt)
                    ac[nt] = MFMA(Aa, Ff[kt][nt], ac[nt], 0, 0, 0);
            }
#pragma unroll
            for (int nt = 0; nt < 2; ++nt) {
                int s = nt * 16 + l15;
                f32x4 ov;
#pragma unroll
                for (int r = 0; r < 4; ++r)
                    ov[r] = fmaf(-dtv, ac[nt][r], u_all[mt][nt][r]);
                *(f32x4*)(st0 + s * 64 + g * 16) = ov;
            }
            asm volatile("s_waitcnt lgkmcnt(0)" ::: "memory");
#pragma unroll
            for (int p = 0; p < 2; ++p) {
                int s  = p * 16 + (lane >> 2);
                int qi = (lane & 3) * 4;
                f32x4 v = *(const f32x4*)(st0 + s * 64 + qi * 4);
                int qb = mt * 16 + qi;
                if (qb < Q)
                    *(f32x4*)(&out[(size_t)(sbase + s) * Q + qb]) = v;
            }
            asm volatile("s_waitcnt lgkmcnt(0)" ::: "memory");
        }
    }
}

extern "C" void kernel_launch(void* const* d_in, const int* in_sizes, int n_in,
                              void* d_out, int out_size, void* d_ws, size_t ws_size,
                              hipStream_t stream) {
    const float* W0 = (const float*)d_in[0];
    const float* b0 = (const float*)d_in[1];
    const float* W1 = (const float*)d_in[2];
    const float* b1 = (const float*)d_in[3];
    const float* W2 = (const float*)d_in[4];
    const float* b2 = (const float*)d_in[5];
    const float* W3 = (const float*)d_in[6];
    const float* b3 = (const float*)d_in[7];
    const float* W4 = (const float*)d_in[8];
    const float* b4 = (const float*)d_in[9];
    const float* W5 = (const float*)d_in[10];
    const float* b5 = (const float*)d_in[11];
    const float* x     = (const float*)d_in[12];
    const float* lam1  = (const float*)d_in[13];
    const float* lam2  = (const float*)d_in[14];
    const float* alpha = (const float*)d_in[15];
    const float* dt    = (const float*)d_in[16];

    unsigned char* ws = (unsigned char*)d_ws;

    build_frags<<<134, 64, 0, stream>>>(W1, W2, W3, W4, W5, alpha, ws);
    pinn_mfma<<<NBLK, BLK, 0, stream>>>(b0, W0, b1, b2, b3, b4, b5,
                                        x, lam1, lam2, dt,
                                        (const unsigned char*)ws, (float*)d_out);
}

// Round 16
// 124.509 us; speedup vs baseline: 1.1731x; 1.0759x over previous
//
#include <hip/hip_runtime.h>
#include <hip/hip_bf16.h>

// PINN via MFMA — round-11 optimum restored exactly (124.9us measured).
// 1-wave workgroups, launch_bounds(64,2), full unroll, VGPR 96 no-spill.
// THREE-kernel setup: compute_w5a (parallel 20x256) -> build_frags -> main.
// (Round 15 lesson: inlining W5a into build_frags serialized an 800-iter
// FMA loop ahead of the main kernel, costing +9us on the graph.)
// out = u - dt*(f@alpha^T); uxx enters linearly -> fast path uses
// W5a = W5@alpha^T when l1==0 (exact); generic path kept for l1!=0.
// d_ws layout (1KB frags, lane*16B within frag):
//   [0,64K):        hidden L=0..3, base L*16K: fid=kt*4+mt hi, +8K lo
//   [64K,92K):      W5: fid=kt*7+mt hi (14), +14K lo
//   [92K,106K):     W5a frags: fid=kt*7+mt hi only (14)
//   [106K,134K):    alpha frags (28, no lo)  [fallback path]
//   [134K,154K):    W5a dense fp32 [50][100]

#define NPTS 262144
#define HW   50
#define Q    100
#define BLK  64
#define SPW  32
#define SPB  32
#define NBLK (NPTS / SPB)

#define WS_W5    65536
#define WS_W5AF  94208
#define WS_ALPHA 108544
#define WS_DENSE 137216

typedef float f32x4 __attribute__((ext_vector_type(4)));
typedef short bf16x8 __attribute__((ext_vector_type(8)));
typedef unsigned int u32x4 __attribute__((ext_vector_type(4)));

#define MFMA __builtin_amdgcn_mfma_f32_16x16x32_bf16

__device__ __forceinline__ unsigned int pack_bf2(float a, float b) {
    __hip_bfloat162 h = __float22bfloat162_rn(make_float2(a, b));
    unsigned int u;
    __builtin_memcpy(&u, &h, 4);   // bit-extract; __hip_bfloat162 not trivially copyable
    return u;
}
__device__ __forceinline__ float lo_f(unsigned int p) {   // low bf16 as float
    return __builtin_bit_cast(float, p << 16);
}
__device__ __forceinline__ float hi_f(unsigned int p) {   // high bf16 as float
    return __builtin_bit_cast(float, p & 0xffff0000u);
}
__device__ __forceinline__ float fast_tanh(float z) {
    float e = __expf(2.0f * z);
    return 1.0f - __fdividef(2.0f, e + 1.0f);
}

// ---------- setup 1: dense W5a[i][q] = sum_j W5[i][j] * alpha[q][j] ----------
__global__ void __launch_bounds__(256, 1)
compute_w5a(const float* __restrict__ W5, const float* __restrict__ alpha,
            float* __restrict__ w5a)
{
    int idx = blockIdx.x * 256 + threadIdx.x;      // 0..4999
    if (idx >= HW * Q) return;
    int i = idx / Q, q = idx - i * Q;
    float acc = 0.0f;
    for (int j = 0; j < Q; ++j)
        acc = fmaf(W5[i * Q + j], alpha[q * Q + j], acc);
    w5a[idx] = acc;
}

// ---------- setup 2: build all A-fragments into d_ws ----------
__global__ void __launch_bounds__(64, 1)
build_frags(const float* __restrict__ W1, const float* __restrict__ W2,
            const float* __restrict__ W3, const float* __restrict__ W4,
            const float* __restrict__ W5, const float* __restrict__ alpha,
            unsigned char* __restrict__ ws)
{
    const int ln  = threadIdx.x;
    const int fid = blockIdx.x;            // 0..133

    const float* src;
    int ld, kmax, mmax, kt, mt;
    bool trans, isLo;
    size_t dst;

    if (fid < 64) {
        int L = fid >> 4, f = fid & 15;
        src = (L == 0) ? W1 : (L == 1) ? W2 : (L == 2) ? W3 : W4;
        ld = HW; kmax = HW; mmax = HW; trans = true;
        isLo = f >= 8;
        int ff = f & 7;
        kt = ff >> 2; mt = ff & 3;
        dst = (size_t)(L * 16384 + f * 1024);
    } else if (fid < 92) {
        int f = fid - 64;                  // 0..27
        src = W5; ld = Q; kmax = HW; mmax = Q; trans = true;
        isLo = f >= 14;
        int ff = isLo ? f - 14 : f;
        kt = ff / 7; mt = ff % 7;
        dst = (size_t)(WS_W5 + f * 1024);
    } else if (fid < 106) {
        int f = fid - 92;                  // 0..13, W5a hi frags
        src = (const float*)(ws + WS_DENSE);
        ld = Q; kmax = HW; mmax = Q; trans = true;
        isLo = false;
        kt = f / 7; mt = f % 7;
        dst = (size_t)(WS_W5AF + f * 1024);
    } else {
        int f = fid - 106;                 // 0..27, alpha (fallback)
        src = alpha; ld = Q; kmax = Q; mmax = Q; trans = false;
        isLo = false;
        kt = f / 7; mt = f % 7;
        dst = (size_t)(WS_ALPHA + f * 1024);
    }

    int m  = mt * 16 + (ln & 15);
    int kb = kt * 32 + (ln >> 4) * 8;
    bool mv = (m < mmax);
    unsigned int wout[4];
#pragma unroll
    for (int jj = 0; jj < 4; ++jj) {
        int k0 = kb + 2 * jj, k1 = k0 + 1;
        float v0 = (mv && k0 < kmax) ? (trans ? src[k0 * ld + m] : src[m * ld + k0]) : 0.0f;
        float v1 = (mv && k1 < kmax) ? (trans ? src[k1 * ld + m] : src[m * ld + k1]) : 0.0f;
        unsigned int h = pack_bf2(v0, v1);
        if (isLo)
            wout[jj] = pack_bf2(v0 - lo_f(h), v1 - hi_f(h));
        else
            wout[jj] = h;
    }
    *(uint4*)(ws + dst + ln * 16) = make_uint4(wout[0], wout[1], wout[2], wout[3]);
}

// ---------- main kernel -----------------------------------------------------
__global__ void __launch_bounds__(BLK, 2)
pinn_mfma(const float* __restrict__ b0v, const float* __restrict__ W0,
          const float* __restrict__ b1, const float* __restrict__ b2,
          const float* __restrict__ b3, const float* __restrict__ b4,
          const float* __restrict__ b5,
          const float* __restrict__ x, const float* __restrict__ lam1p,
          const float* __restrict__ lam2p, const float* __restrict__ dtp,
          const unsigned char* __restrict__ ws, float* __restrict__ out)
{
    __shared__ __align__(16) unsigned char statebuf[8192];

    const int lane = threadIdx.x & 63;
    const int l15  = lane & 15;
    const int g    = lane >> 4;
    const int sbase = blockIdx.x * SPB;

    unsigned char* st0 = &statebuf[0];
    unsigned char* st1 = &statebuf[4096];
    const unsigned char* wgl = ws + lane * 16;   // per-lane base into frag store
    const int swz = (l15 & 7) << 4;   // samp&7 == l15&7 (samp = 16nt + l15)

    const f32x4 Z4 = {0.0f, 0.0f, 0.0f, 0.0f};

    // persistent state B-fragments: B[k=ch][n=samp], elem j -> ch = 32kt+8g+j
    bf16x8 Bh_hi[2][2], Bh_lo[2][2], Bx[2][2], Bxx[2][2];

    // ---------- layer 0: 1 -> 50 (analytic, elementwise) ----------
    {
        float xv[2];
        xv[0] = x[sbase + l15];
        xv[1] = x[sbase + 16 + l15];
#pragma unroll
        for (int kt = 0; kt < 2; ++kt) {
            float wv[8], bv[8];
#pragma unroll
            for (int j = 0; j < 8; ++j) {
                int ch = kt * 32 + g * 8 + j;
                wv[j] = (ch < HW) ? W0[ch] : 0.0f;
                bv[j] = (ch < HW) ? b0v[ch] : 0.0f;
            }
#pragma unroll
            for (int nt = 0; nt < 2; ++nt) {
                u32x4 uh, ul, ux, uxx;
#pragma unroll
                for (int jp = 0; jp < 4; ++jp) {
                    float t0 = fast_tanh(fmaf(xv[nt], wv[2*jp],   bv[2*jp]));
                    float t1 = fast_tanh(fmaf(xv[nt], wv[2*jp+1], bv[2*jp+1]));
                    float s0 = 1.0f - t0 * t0, s1 = 1.0f - t1 * t1;
                    float hx0 = s0 * wv[2*jp],   hx1 = s1 * wv[2*jp+1];
                    float hxx0 = -2.0f * t0 * hx0 * wv[2*jp];
                    float hxx1 = -2.0f * t1 * hx1 * wv[2*jp+1];
                    unsigned int h = pack_bf2(t0, t1);
                    uh[jp]  = h;
                    ul[jp]  = pack_bf2(t0 - lo_f(h), t1 - hi_f(h));
                    ux[jp]  = pack_bf2(hx0, hx1);
                    uxx[jp] = pack_bf2(hxx0, hxx1);
                }
                Bh_hi[kt][nt] = __builtin_bit_cast(bf16x8, uh);
                Bh_lo[kt][nt] = __builtin_bit_cast(bf16x8, ul);
                Bx[kt][nt]    = __builtin_bit_cast(bf16x8, ux);
                Bxx[kt][nt]   = __builtin_bit_cast(bf16x8, uxx);
            }
        }
    }

    // ---------- 4 hidden layers 50 -> 50 ----------
    for (int L = 0; L < 4; ++L) {
        const float* bl = (L == 0) ? b1 : (L == 1) ? b2 : (L == 2) ? b3 : b4;
        const unsigned char* wfl = wgl + L * 16384;

        float bb[4][4];
#pragma unroll
        for (int mt = 0; mt < 4; ++mt)
#pragma unroll
            for (int r = 0; r < 4; ++r) {
                int ch = mt * 16 + g * 4 + r;
                bb[mt][r] = (ch < HW) ? bl[ch] : 0.0f;
            }

        // accumulators; at pre-seeded with bias (saves the add before tanh)
        f32x4 at[4][2], ax[4][2], axx[4][2];
#pragma unroll
        for (int mt = 0; mt < 4; ++mt)
#pragma unroll
            for (int nt = 0; nt < 2; ++nt) {
#pragma unroll
                for (int r = 0; r < 4; ++r) at[mt][nt][r] = bb[mt][r];
                ax[mt][nt] = Z4; axx[mt][nt] = Z4;
            }

#pragma unroll
        for (int kt = 0; kt < 2; ++kt) {
#pragma unroll
            for (int mt = 0; mt < 4; ++mt) {
                bf16x8 Ahi = *(const bf16x8*)(wfl + (kt * 4 + mt) * 1024);
                bf16x8 Alo = *(const bf16x8*)(wfl + (8 + kt * 4 + mt) * 1024);
#pragma unroll
                for (int nt = 0; nt < 2; ++nt) {
                    at[mt][nt]  = MFMA(Ahi, Bh_hi[kt][nt], at[mt][nt], 0, 0, 0);
                    at[mt][nt]  = MFMA(Ahi, Bh_lo[kt][nt], at[mt][nt], 0, 0, 0);
                    at[mt][nt]  = MFMA(Alo, Bh_hi[kt][nt], at[mt][nt], 0, 0, 0);
                    ax[mt][nt]  = MFMA(Ahi, Bx[kt][nt],  ax[mt][nt],  0, 0, 0);
                    axx[mt][nt] = MFMA(Ahi, Bxx[kt][nt], axx[mt][nt], 0, 0, 0);
                }
            }
        }

        // phase A: t = tanh(z); stage hi/lo -> read new Bh frags
#pragma unroll
        for (int mt = 0; mt < 4; ++mt)
#pragma unroll
            for (int nt = 0; nt < 2; ++nt) {
                float t0 = fast_tanh(at[mt][nt][0]);
                float t1 = fast_tanh(at[mt][nt][1]);
                float t2 = fast_tanh(at[mt][nt][2]);
                float t3 = fast_tanh(at[mt][nt][3]);
                at[mt][nt][0] = t0; at[mt][nt][1] = t1;
                at[mt][nt][2] = t2; at[mt][nt][3] = t3;
                unsigned int h0 = pack_bf2(t0, t1);
                unsigned int h1 = pack_bf2(t2, t3);
                unsigned int l0 = pack_bf2(t0 - lo_f(h0), t1 - hi_f(h0));
                unsigned int l1 = pack_bf2(t2 - lo_f(h1), t3 - hi_f(h1));
                int off = ((nt * 16 + l15) * 128 + (mt * 16 + g * 4) * 2) ^ swz;
                *(uint2*)(st0 + off) = make_uint2(h0, h1);
                *(uint2*)(st1 + off) = make_uint2(l0, l1);
            }
#pragma unroll
        for (int kt = 0; kt < 2; ++kt)
#pragma unroll
            for (int nt = 0; nt < 2; ++nt) {
                int off = ((nt * 16 + l15) * 128 + (kt * 32 + g * 8) * 2) ^ swz;
                Bh_hi[kt][nt] = *(const bf16x8*)(st0 + off);
                Bh_lo[kt][nt] = *(const bf16x8*)(st1 + off);
            }
        asm volatile("s_waitcnt lgkmcnt(0)" ::: "memory");

        // phase B: hx = s*zx ; hxx = s*zxx - 2*t*s*zx^2
#pragma unroll
        for (int mt = 0; mt < 4; ++mt)
#pragma unroll
            for (int nt = 0; nt < 2; ++nt) {
                float hx[4], hxx[4];
#pragma unroll
                for (int r = 0; r < 4; ++r) {
                    float t   = at[mt][nt][r];
                    float s   = fmaf(-t, t, 1.0f);
                    float zx  = ax[mt][nt][r];
                    float zxx = axx[mt][nt][r];
                    hx[r]  = s * zx;
                    hxx[r] = fmaf(s, zxx, -2.0f * t * zx * hx[r]);
                }
                unsigned int a0 = pack_bf2(hx[0], hx[1]);
                unsigned int a1 = pack_bf2(hx[2], hx[3]);
                unsigned int c0 = pack_bf2(hxx[0], hxx[1]);
                unsigned int c1 = pack_bf2(hxx[2], hxx[3]);
                int off = ((nt * 16 + l15) * 128 + (mt * 16 + g * 4) * 2) ^ swz;
                *(uint2*)(st0 + off) = make_uint2(a0, a1);
                *(uint2*)(st1 + off) = make_uint2(c0, c1);
            }
#pragma unroll
        for (int kt = 0; kt < 2; ++kt)
#pragma unroll
            for (int nt = 0; nt < 2; ++nt) {
                int off = ((nt * 16 + l15) * 128 + (kt * 32 + g * 8) * 2) ^ swz;
                Bx[kt][nt]  = *(const bf16x8*)(st0 + off);
                Bxx[kt][nt] = *(const bf16x8*)(st1 + off);
            }
        asm volatile("s_waitcnt lgkmcnt(0)" ::: "memory");
    }

    const float lam1 = lam1p[0];
    const float el2  = __expf(lam2p[0]);
    const float dtv  = dtp[0];

    const unsigned char* w5f = wgl + WS_W5;

    if (lam1 == 0.0f) {
        // ======== FAST PATH: out = (h@W5+b5) - dt*el2*(hxx@W5a) ========
        const unsigned char* waf = wgl + WS_W5AF;
        const float c = dtv * el2;
#pragma unroll
        for (int mt = 0; mt < 7; ++mt) {
            f32x4 au[2], acr[2];
#pragma unroll
            for (int nt = 0; nt < 2; ++nt) {
#pragma unroll
                for (int r = 0; r < 4; ++r) {
                    int q = mt * 16 + g * 4 + r;
                    au[nt][r] = (q < Q) ? b5[q] : 0.0f;
                }
                acr[nt] = Z4;
            }
#pragma unroll
            for (int kt = 0; kt < 2; ++kt) {
                bf16x8 Ahi = *(const bf16x8*)(w5f + (kt * 7 + mt) * 1024);
                bf16x8 Alo = *(const bf16x8*)(w5f + (14 + kt * 7 + mt) * 1024);
                bf16x8 Aa  = *(const bf16x8*)(waf + (kt * 7 + mt) * 1024);
#pragma unroll
                for (int nt = 0; nt < 2; ++nt) {
                    au[nt]  = MFMA(Ahi, Bh_hi[kt][nt], au[nt],  0, 0, 0);
                    au[nt]  = MFMA(Ahi, Bh_lo[kt][nt], au[nt],  0, 0, 0);
                    au[nt]  = MFMA(Alo, Bh_hi[kt][nt], au[nt],  0, 0, 0);
                    acr[nt] = MFMA(Aa,  Bxx[kt][nt],   acr[nt], 0, 0, 0);
                }
            }
            // combine, stage [32 samp][16 q] fp32 in st0, coalesced store
#pragma unroll
            for (int nt = 0; nt < 2; ++nt) {
                int s = nt * 16 + l15;
                f32x4 ov;
#pragma unroll
                for (int r = 0; r < 4; ++r)
                    ov[r] = fmaf(-c, acr[nt][r], au[nt][r]);
                *(f32x4*)(st0 + s * 64 + g * 16) = ov;
            }
            asm volatile("s_waitcnt lgkmcnt(0)" ::: "memory");
#pragma unroll
            for (int p = 0; p < 2; ++p) {
                int s  = p * 16 + (lane >> 2);
                int qi = (lane & 3) * 4;
                f32x4 v = *(const f32x4*)(st0 + s * 64 + qi * 4);
                int qb = mt * 16 + qi;
                if (qb < Q)
                    *(f32x4*)(&out[(size_t)(sbase + s) * Q + qb]) = v;
            }
            asm volatile("s_waitcnt lgkmcnt(0)" ::: "memory");
        }
    } else {
        // ======== GENERIC PATH (proven round-8 code) ========
        f32x4 u_all[7][2];
#pragma unroll
        for (int mt = 0; mt < 7; ++mt) {
            f32x4 au[2], aux_[2], auxx[2];
#pragma unroll
            for (int nt = 0; nt < 2; ++nt) {
#pragma unroll
                for (int r = 0; r < 4; ++r) {
                    int q = mt * 16 + g * 4 + r;
                    au[nt][r] = (q < Q) ? b5[q] : 0.0f;
                }
                aux_[nt] = Z4; auxx[nt] = Z4;
            }
#pragma unroll
            for (int kt = 0; kt < 2; ++kt) {
                bf16x8 Ahi = *(const bf16x8*)(w5f + (kt * 7 + mt) * 1024);
                bf16x8 Alo = *(const bf16x8*)(w5f + (14 + kt * 7 + mt) * 1024);
#pragma unroll
                for (int nt = 0; nt < 2; ++nt) {
                    au[nt]   = MFMA(Ahi, Bh_hi[kt][nt], au[nt],   0, 0, 0);
                    au[nt]   = MFMA(Ahi, Bh_lo[kt][nt], au[nt],   0, 0, 0);
                    au[nt]   = MFMA(Alo, Bh_hi[kt][nt], au[nt],   0, 0, 0);
                    aux_[nt] = MFMA(Ahi, Bx[kt][nt],  aux_[nt], 0, 0, 0);
                    auxx[nt] = MFMA(Ahi, Bxx[kt][nt], auxx[nt], 0, 0, 0);
                }
            }
#pragma unroll
            for (int nt = 0; nt < 2; ++nt) {
                float fv[4];
#pragma unroll
                for (int r = 0; r < 4; ++r) {
                    int q = mt * 16 + g * 4 + r;
                    float u = au[nt][r];
                    u_all[mt][nt][r] = u;
                    float f = fmaf(-lam1 * u, aux_[nt][r], el2 * auxx[nt][r]);
                    fv[r] = (q < Q) ? f : 0.0f;
                }
                unsigned int f0 = pack_bf2(fv[0], fv[1]);
                unsigned int f1 = pack_bf2(fv[2], fv[3]);
                int s = nt * 16 + l15;
                int off = (s * 256 + (mt * 16 + g * 4) * 2) ^ swz;
                *(uint2*)(st0 + off) = make_uint2(f0, f1);
            }
        }

        bf16x8 Ff[4][2];
#pragma unroll
        for (int kt = 0; kt < 4; ++kt)
#pragma unroll
            for (int nt = 0; nt < 2; ++nt) {
                int s = nt * 16 + l15;
                int off = (s * 256 + (kt * 32 + g * 8) * 2) ^ swz;
                Ff[kt][nt] = *(const bf16x8*)(st0 + off);
            }
        asm volatile("s_waitcnt lgkmcnt(0)" ::: "memory");
        {
            const bf16x8 z8 = {0, 0, 0, 0, 0, 0, 0, 0};
            if (g >= 2) { Ff[3][0] = z8; Ff[3][1] = z8; }
        }

        const unsigned char* alf = wgl + WS_ALPHA;
#pragma unroll
        for (int mt = 0; mt < 7; ++mt) {
            f32x4 ac[2]; ac[0] = Z4; ac[1] = Z4;
#pragma unroll
            for (int kt = 0; kt < 4; ++kt) {
                bf16x8 Aa = *(const bf16x8*)(alf + (kt * 7 + mt) * 1024);
#pragma unroll
                for (int nt = 0; nt < 2; ++nt)
                    ac[nt] = MFMA(Aa, Ff[kt][nt], ac[nt], 0, 0, 0);
            }
#pragma unroll
            for (int nt = 0; nt < 2; ++nt) {
                int s = nt * 16 + l15;
                f32x4 ov;
#pragma unroll
                for (int r = 0; r < 4; ++r)
                    ov[r] = fmaf(-dtv, ac[nt][r], u_all[mt][nt][r]);
                *(f32x4*)(st0 + s * 64 + g * 16) = ov;
            }
            asm volatile("s_waitcnt lgkmcnt(0)" ::: "memory");
#pragma unroll
            for (int p = 0; p < 2; ++p) {
                int s  = p * 16 + (lane >> 2);
                int qi = (lane & 3) * 4;
                f32x4 v = *(const f32x4*)(st0 + s * 64 + qi * 4);
                int qb = mt * 16 + qi;
                if (qb < Q)
                    *(f32x4*)(&out[(size_t)(sbase + s) * Q + qb]) = v;
            }
            asm volatile("s_waitcnt lgkmcnt(0)" ::: "memory");
        }
    }
}

extern "C" void kernel_launch(void* const* d_in, const int* in_sizes, int n_in,
                              void* d_out, int out_size, void* d_ws, size_t ws_size,
                              hipStream_t stream) {
    const float* W0 = (const float*)d_in[0];
    const float* b0 = (const float*)d_in[1];
    const float* W1 = (const float*)d_in[2];
    const float* b1 = (const float*)d_in[3];
    const float* W2 = (const float*)d_in[4];
    const float* b2 = (const float*)d_in[5];
    const float* W3 = (const float*)d_in[6];
    const float* b3 = (const float*)d_in[7];
    const float* W4 = (const float*)d_in[8];
    const float* b4 = (const float*)d_in[9];
    const float* W5 = (const float*)d_in[10];
    const float* b5 = (const float*)d_in[11];
    const float* x     = (const float*)d_in[12];
    const float* lam1  = (const float*)d_in[13];
    const float* lam2  = (const float*)d_in[14];
    const float* alpha = (const float*)d_in[15];
    const float* dt    = (const float*)d_in[16];

    unsigned char* ws = (unsigned char*)d_ws;

    compute_w5a<<<20, 256, 0, stream>>>(W5, alpha, (float*)(ws + WS_DENSE));
    build_frags<<<134, 64, 0, stream>>>(W1, W2, W3, W4, W5, alpha, ws);
    pinn_mfma<<<NBLK, BLK, 0, stream>>>(b0, W0, b1, b2, b3, b4, b5,
                                        x, lam1, lam2, dt,
                                        (const unsigned char*)ws, (float*)d_out);
}